// Round 4
// baseline (135.831 us; speedup 1.0000x reference)
//
#include <hip/hip_runtime.h>
#include <hip/hip_bf16.h>

#define BT    8192      // B*T tokens (4*2048)
#define SEQ_T 2048
#define DIN   1024
#define NH    16
#define NK    8
#define DH    64
#define DO    64

typedef __bf16 bf16;
typedef __attribute__((ext_vector_type(8))) __bf16 bf16x8;
typedef __attribute__((ext_vector_type(4))) __bf16 bf16x4;
typedef __attribute__((ext_vector_type(4))) float floatx4;

// ---------------------------------------------------------------------------
// Kernel 1 (R2 structure, 1 token/wave — the 10 µs version; R3's 2-tok/wave
// regressed 3x, reverted):
//   (a) scores_t[k][token] = phi[t,k] + x[token,:]·diag[k,:]  (fp32)
//   (b) xb[token][i] = bf16(x[token][i])   (bf16 copy of x for moe's A side)
//   (c) wt[h][k][o][i] = bf16(W[h][k][i][o]) via LDS transpose.
// ---------------------------------------------------------------------------
__global__ __launch_bounds__(256) void prep_kernel(
    const float* __restrict__ x, const float* __restrict__ weight,
    const float* __restrict__ diag, const float* __restrict__ phi,
    float* __restrict__ scores_t, bf16* __restrict__ wt, bf16* __restrict__ xb)
{
  int blk = blockIdx.x, tid = threadIdx.x;
  if (blk < BT / 4) {
    // ---- scores + bf16 conversion: one wave per token ----
    int wave = tid >> 6, lane = tid & 63;
    int token = blk * 4 + wave;
    const floatx4* xr = (const floatx4*)(x + (size_t)token * DIN);
    const floatx4* dg = (const floatx4*)diag;
    floatx4 acc[NK];
#pragma unroll
    for (int k = 0; k < NK; k++) acc[k] = (floatx4){0.f, 0.f, 0.f, 0.f};
#pragma unroll
    for (int it = 0; it < 4; it++) {
      floatx4 xv = xr[it * 64 + lane];
      // bf16 copy (coalesced 8B/lane stores)
      bf16x4 c;
      c[0] = (bf16)xv[0]; c[1] = (bf16)xv[1];
      c[2] = (bf16)xv[2]; c[3] = (bf16)xv[3];
      *(bf16x4*)(xb + (size_t)token * DIN + it * 256 + lane * 4) = c;
#pragma unroll
      for (int k = 0; k < NK; k++) {
        floatx4 dv = dg[k * 256 + it * 64 + lane];
        acc[k] += xv * dv;
      }
    }
    float r[NK];
#pragma unroll
    for (int k = 0; k < NK; k++)
      r[k] = (acc[k][0] + acc[k][1]) + (acc[k][2] + acc[k][3]);
#pragma unroll
    for (int k = 0; k < NK; k++) {
      float v = r[k];
#pragma unroll
      for (int off = 32; off >= 1; off >>= 1) v += __shfl_xor(v, off, 64);
      r[k] = v;
    }
    if (lane == 0) {
      int t = token & (SEQ_T - 1);
#pragma unroll
      for (int k = 0; k < NK; k++)
        scores_t[(size_t)k * BT + token] = phi[t * NK + k] + r[k];
    }
  } else {
    // ---- weight transpose: one (h,k) 64x64 tile per block, coalesced ----
    __shared__ bf16 tile[64 * 68];
    int hk = blk - BT / 4;
    const float* wsrc = weight + (size_t)hk * DH * DO;
#pragma unroll
    for (int it = 0; it < 4; it++) {
      int idx = it * 1024 + tid * 4;
      int i = idx >> 6, o = idx & 63;
      floatx4 v = *(const floatx4*)(wsrc + idx);
#pragma unroll
      for (int r = 0; r < 4; r++)
        tile[(o + r) * 68 + i] = (bf16)v[r];
    }
    __syncthreads();
#pragma unroll
    for (int it = 0; it < 4; it++) {
      int idx = it * 1024 + tid * 4;
      int o2 = idx >> 6, i2 = idx & 63;
      bf16x4 v = *(const bf16x4*)&tile[o2 * 68 + i2];
      *(bf16x4*)(wt + (size_t)hk * 4096 + idx) = v;
    }
  }
}

// ---------------------------------------------------------------------------
// Kernel 2 (v4): NO LDS, no barriers. Block = (128-token group, head h),
// 4 waves; wave owns a 16-col slice, all 8 experts' B frags persistent in
// registers (64 VGPRs). A now loads DIRECTLY as bf16x8 from xb: 4 loads/tile
// (was 8 fp32 + 16-op repack), double-buffer = 32 VGPRs (was 64) so the
// whole pipeline fits under the 128-VGPR / 4-blocks-per-CU budget.
// ---------------------------------------------------------------------------
__global__ __launch_bounds__(256, 4) void moe_kernel(
    const bf16* __restrict__ xb, const bf16* __restrict__ wt,
    const float* __restrict__ scores_t, float* __restrict__ out)
{
  int g = blockIdx.x >> 4;            // token group 0..63 (128 tokens)
  int h = blockIdx.x & (NH - 1);
  int tid = threadIdx.x, lane = tid & 63, w = tid >> 6;
  int l15 = lane & 15, q = lane >> 4;
  int C0 = w * 16;
  int tg0 = g * 128;

  // ---- persistent B fragments: B[i=ki*32+q*8+j][o=C0+l15] ----
  bf16x8 b[NK][2];
  {
    const bf16* wh = wt + (size_t)h * NK * DO * DH;
#pragma unroll
    for (int k = 0; k < NK; k++) {
      const bf16* bp = wh + ((size_t)k * DO + C0 + l15) * DH + q * 8;
      b[k][0] = *(const bf16x8*)bp;
      b[k][1] = *(const bf16x8*)(bp + 32);
    }
  }

  const bf16* xc = xb + (size_t)h * DH;   // head's 64-col slice, bf16 rows
  bf16x8 a[2][2][2];                      // [buf][rb][ki], 32 VGPRs

  // ---- tile 0 A loads ----
#pragma unroll
  for (int rb = 0; rb < 2; rb++) {
    const bf16* rp = xc + (size_t)(tg0 + rb * 16 + l15) * DIN + q * 8;
    a[0][rb][0] = *(const bf16x8*)rp;
    a[0][rb][1] = *(const bf16x8*)(rp + 32);
  }

#pragma unroll
  for (int t = 0; t < 4; t++) {
    int tr = tg0 + t * 32;
    if (t < 3) {   // prefetch next tile into other buffer
#pragma unroll
      for (int rb = 0; rb < 2; rb++) {
        const bf16* rp = xc + (size_t)(tr + 32 + rb * 16 + l15) * DIN + q * 8;
        a[(t + 1) & 1][rb][0] = *(const bf16x8*)rp;
        a[(t + 1) & 1][rb][1] = *(const bf16x8*)(rp + 32);
      }
    }
    floatx4 y0 = (floatx4){0.f, 0.f, 0.f, 0.f};
    floatx4 y1 = (floatx4){0.f, 0.f, 0.f, 0.f};
#pragma unroll
    for (int k = 0; k < NK; k++) {
      floatx4 s0 = *(const floatx4*)(scores_t + (size_t)k * BT + tr + q * 4);
      floatx4 s1 = *(const floatx4*)(scores_t + (size_t)k * BT + tr + 16 + q * 4);
      floatx4 z0 = (floatx4){0.f, 0.f, 0.f, 0.f};
      z0 = __builtin_amdgcn_mfma_f32_16x16x32_bf16(a[t & 1][0][0], b[k][0], z0, 0, 0, 0);
      z0 = __builtin_amdgcn_mfma_f32_16x16x32_bf16(a[t & 1][0][1], b[k][1], z0, 0, 0, 0);
      y0 += s0 * z0;
      floatx4 z1 = (floatx4){0.f, 0.f, 0.f, 0.f};
      z1 = __builtin_amdgcn_mfma_f32_16x16x32_bf16(a[t & 1][1][0], b[k][0], z1, 0, 0, 0);
      z1 = __builtin_amdgcn_mfma_f32_16x16x32_bf16(a[t & 1][1][1], b[k][1], z1, 0, 0, 0);
      y1 += s1 * z1;
    }
    // ---- store: C/D layout col=l15, row=q*4+r ----
#pragma unroll
    for (int r = 0; r < 4; r++) {
      out[(size_t)(tr + q * 4 + r) * (NH * DO) + h * DO + C0 + l15]      = y0[r];
      out[(size_t)(tr + 16 + q * 4 + r) * (NH * DO) + h * DO + C0 + l15] = y1[r];
    }
  }
}

extern "C" void kernel_launch(void* const* d_in, const int* in_sizes, int n_in,
                              void* d_out, int out_size, void* d_ws, size_t ws_size,
                              hipStream_t stream) {
  const float* x      = (const float*)d_in[0];
  const float* weight = (const float*)d_in[1];
  const float* diag   = (const float*)d_in[2];
  const float* phi    = (const float*)d_in[3];
  float* out = (float*)d_out;

  // workspace: [0,1MiB) wt (bf16) | [1MiB,1.25MiB) scores_t | [2MiB,18MiB) xb
  bf16*  wt       = (bf16*)d_ws;
  float* scores_t = (float*)((char*)d_ws + (1u << 20));
  bf16*  xb       = (bf16*)((char*)d_ws + (2u << 20));

  prep_kernel<<<BT / 4 + NH * NK, 256, 0, stream>>>(x, weight, diag, phi,
                                                    scores_t, wt, xb);
  moe_kernel<<<64 * NH, 256, 0, stream>>>(xb, wt, scores_t, out);
}

// Round 5
// 114.723 us; speedup vs baseline: 1.1840x; 1.1840x over previous
//
#include <hip/hip_runtime.h>
#include <hip/hip_bf16.h>

#define BT    8192      // B*T tokens (4*2048)
#define SEQ_T 2048
#define DIN   1024
#define NH    16
#define NK    8
#define DH    64
#define DO    64
#define XPAD  72        // padded row length (bf16) for xh / wt rows: stride
                        // 144 B = 36 dwords = 4 mod 32 banks -> 2-way (free)

typedef __bf16 bf16;
typedef __attribute__((ext_vector_type(8))) __bf16 bf16x8;
typedef __attribute__((ext_vector_type(4))) __bf16 bf16x4;
typedef __attribute__((ext_vector_type(4))) float floatx4;

// ---------------------------------------------------------------------------
// Kernel 1: (a) scores_t[k][token] = phi[t,k] + x[token,:]·diag[k,:]  (fp32)
//           (b) xh[h][token][0..63 (pad 72)] = bf16(x[token][h*64+c])
//               head-major so moe's x staging is a contiguous block read
//           (c) wt[h*8+k][o][0..63 (pad 72)] = bf16(W[h][k][i][o]) transposed
// ---------------------------------------------------------------------------
__global__ __launch_bounds__(256) void prep_kernel(
    const float* __restrict__ x, const float* __restrict__ weight,
    const float* __restrict__ diag, const float* __restrict__ phi,
    float* __restrict__ scores_t, bf16* __restrict__ wt, bf16* __restrict__ xh)
{
  int blk = blockIdx.x, tid = threadIdx.x;
  if (blk < BT / 4) {
    // ---- scores + head-major bf16 copy: one wave per token ----
    int wave = tid >> 6, lane = tid & 63;
    int token = blk * 4 + wave;
    const floatx4* xr = (const floatx4*)(x + (size_t)token * DIN);
    const floatx4* dg = (const floatx4*)diag;
    floatx4 acc[NK];
#pragma unroll
    for (int k = 0; k < NK; k++) acc[k] = (floatx4){0.f, 0.f, 0.f, 0.f};
#pragma unroll
    for (int it = 0; it < 4; it++) {
      floatx4 xv = xr[it * 64 + lane];
      // head-major bf16 copy: col = it*256 + lane*4 -> h = col>>6, c = col&63
      int col = it * 256 + lane * 4;
      int h = col >> 6, c = col & 63;
      bf16x4 cv;
      cv[0] = (bf16)xv[0]; cv[1] = (bf16)xv[1];
      cv[2] = (bf16)xv[2]; cv[3] = (bf16)xv[3];
      *(bf16x4*)(xh + ((size_t)h * BT + token) * XPAD + c) = cv;
#pragma unroll
      for (int k = 0; k < NK; k++) {
        floatx4 dv = dg[k * 256 + it * 64 + lane];
        acc[k] += xv * dv;
      }
    }
    float r[NK];
#pragma unroll
    for (int k = 0; k < NK; k++)
      r[k] = (acc[k][0] + acc[k][1]) + (acc[k][2] + acc[k][3]);
#pragma unroll
    for (int k = 0; k < NK; k++) {
      float v = r[k];
#pragma unroll
      for (int off = 32; off >= 1; off >>= 1) v += __shfl_xor(v, off, 64);
      r[k] = v;
    }
    if (lane == 0) {
      int t = token & (SEQ_T - 1);
#pragma unroll
      for (int k = 0; k < NK; k++)
        scores_t[(size_t)k * BT + token] = phi[t * NK + k] + r[k];
    }
  } else {
    // ---- weight transpose: one (h,k) 64x64 tile per block, padded rows ----
    __shared__ bf16 tile[64 * 68];
    int hk = blk - BT / 4;
    const float* wsrc = weight + (size_t)hk * DH * DO;
#pragma unroll
    for (int it = 0; it < 4; it++) {
      int idx = it * 1024 + tid * 4;
      int i = idx >> 6, o = idx & 63;
      floatx4 v = *(const floatx4*)(wsrc + idx);
#pragma unroll
      for (int r = 0; r < 4; r++)
        tile[(o + r) * 68 + i] = (bf16)v[r];
    }
    __syncthreads();
#pragma unroll
    for (int it = 0; it < 4; it++) {
      int idx = it * 1024 + tid * 4;
      int o2 = idx >> 6, i2 = idx & 63;
      bf16x4 v = *(const bf16x4*)&tile[o2 * 68 + i2];
      *(bf16x4*)(wt + ((size_t)hk * DO + o2) * XPAD + i2) = v;
    }
  }
}

// ---------------------------------------------------------------------------
// Kernel 2 (v5): ALL-LDS operands. Block = (128-token group g, head h,
// col-half nh), 256 threads / 4 waves. LDS: x tile 18 KB + W half 36 KB +
// scores 4 KB = 58 KB -> 2 blocks/CU so staging overlaps compute across
// blocks. Every MFMA operand is a ds_read_b128 with 2-way-aliased banks
// (free) -> lgkmcnt-scheduled, no vmcnt(0) latency chains in the loop.
// Wave = (token-half mh, 16-col slice ns): 4 m-tiles x 8 experts x 2 K.
// ---------------------------------------------------------------------------
__global__ __launch_bounds__(256, 2) void moe_kernel(
    const bf16* __restrict__ xh, const bf16* __restrict__ wt,
    const float* __restrict__ scores_t, float* __restrict__ out)
{
  __shared__ bf16  xl[128 * XPAD];        // 18432 B
  __shared__ bf16  wl[NK * 32 * XPAD];    // 36864 B
  __shared__ float sl[NK * 128];          //  4096 B

  int bid = blockIdx.x;
  int g  = bid >> 5;            // 0..63  (128-token groups)
  int h  = (bid >> 1) & 15;
  int nh = bid & 1;             // col half (32 cols of the head's 64)
  int tid = threadIdx.x, lane = tid & 63, w = tid >> 6;
  int l15 = lane & 15, q = lane >> 4;

  // ---- stage x tile: contiguous 18 KB (1152 16-B chunks) ----
  {
    const bf16* src = xh + ((size_t)h * BT + g * 128) * XPAD;
#pragma unroll
    for (int it = 0; it < 5; it++) {
      int idx = it * 256 + tid;
      if (idx < 128 * XPAD / 8) {
        bf16x8 v = *(const bf16x8*)(src + idx * 8);
        *(bf16x8*)(xl + idx * 8) = v;
      }
    }
  }
  // ---- stage W half: 8 experts x 32 o-rows x 72 (2304 chunks, 9/thread) ----
  {
#pragma unroll
    for (int it = 0; it < 9; it++) {
      int idx = it * 256 + tid;          // 0..2303
      int e = idx / 288, r = idx - e * 288;
      const bf16* src = wt + ((size_t)(h * NK + e) * DO + nh * 32) * XPAD + r * 8;
      bf16x8 v = *(const bf16x8*)src;
      *(bf16x8*)(wl + (size_t)e * 32 * XPAD + r * 8) = v;
    }
  }
  // ---- stage scores: 8 experts x 128 tokens fp32 ----
  {
    int k = tid >> 5, t4 = (tid & 31) * 4;
    floatx4 v = *(const floatx4*)(scores_t + (size_t)k * BT + g * 128 + t4);
    *(floatx4*)(sl + k * 128 + t4) = v;
  }
  __syncthreads();

  int mh = w >> 1;              // token half (64 rows)
  int ns = w & 1;               // 16-col slice within the 32-col half

  // ---- B fragments: B[i=ki*32+q*8+j][o=ns*16+l15], all 8 experts ----
  bf16x8 b[NK][2];
#pragma unroll
  for (int e = 0; e < NK; e++)
#pragma unroll
    for (int ki = 0; ki < 2; ki++)
      b[e][ki] = *(const bf16x8*)(wl + ((size_t)e * 32 + ns * 16 + l15) * XPAD
                                     + ki * 32 + q * 8);

#pragma unroll
  for (int m = 0; m < 4; m++) {
    int tr = mh * 64 + m * 16;                         // token row in block
    const bf16* ar = xl + (size_t)(tr + l15) * XPAD + q * 8;
    bf16x8 a0 = *(const bf16x8*)ar;
    bf16x8 a1 = *(const bf16x8*)(ar + 32);
    floatx4 y = (floatx4){0.f, 0.f, 0.f, 0.f};
#pragma unroll
    for (int e = 0; e < NK; e++) {
      floatx4 s4 = *(const floatx4*)(sl + e * 128 + tr + q * 4);
      floatx4 z = (floatx4){0.f, 0.f, 0.f, 0.f};
      z = __builtin_amdgcn_mfma_f32_16x16x32_bf16(a0, b[e][0], z, 0, 0, 0);
      z = __builtin_amdgcn_mfma_f32_16x16x32_bf16(a1, b[e][1], z, 0, 0, 0);
      y += s4 * z;
    }
    // store: C/D layout col=l15, row=q*4+r
    int row = g * 128 + tr + q * 4;
    float* op = out + (size_t)row * (NH * DO) + h * DO + nh * 32 + ns * 16 + l15;
#pragma unroll
    for (int r = 0; r < 4; r++)
      op[(size_t)r * (NH * DO)] = y[r];
  }
}

extern "C" void kernel_launch(void* const* d_in, const int* in_sizes, int n_in,
                              void* d_out, int out_size, void* d_ws, size_t ws_size,
                              hipStream_t stream) {
  const float* x      = (const float*)d_in[0];
  const float* weight = (const float*)d_in[1];
  const float* diag   = (const float*)d_in[2];
  const float* phi    = (const float*)d_in[3];
  float* out = (float*)d_out;

  // workspace: [0, 1.2MiB) wt padded | [2MiB) scores_t 256KiB | [4MiB) xh 18MiB
  bf16*  wt       = (bf16*)d_ws;
  float* scores_t = (float*)((char*)d_ws + (2u << 20));
  bf16*  xh       = (bf16*)((char*)d_ws + (4u << 20));

  prep_kernel<<<BT / 4 + NH * NK, 256, 0, stream>>>(x, weight, diag, phi,
                                                    scores_t, wt, xh);
  // 64 token-groups x 16 heads x 2 col-halves
  moe_kernel<<<64 * NH * 2, 256, 0, stream>>>(xh, wt, scores_t, out);
}

// Round 6
// 108.898 us; speedup vs baseline: 1.2473x; 1.0535x over previous
//
#include <hip/hip_runtime.h>
#include <hip/hip_bf16.h>

#define BT    8192      // B*T tokens (4*2048)
#define SEQ_T 2048
#define DIN   1024
#define NH    16
#define NK    8
#define DH    64
#define DO    64

typedef __bf16 bf16;
typedef __attribute__((ext_vector_type(8))) __bf16 bf16x8;
typedef __attribute__((ext_vector_type(4))) __bf16 bf16x4;
typedef __attribute__((ext_vector_type(4))) float floatx4;

// ---------------------------------------------------------------------------
// Kernel 1: (a) scores_t[k][token] = phi[t,k] + x[token,:]·diag[k,:]  (fp32)
//           (b) xh[h][token][0..63] = bf16(x[token][h*64+c])   (dense, head-
//               major; 16 consecutive lanes write one 128-B row -> coalesced)
//           (c) wt[h*8+k][o][0..63] = bf16(W[h][k][i][o])  (dense transpose)
// ---------------------------------------------------------------------------
__global__ __launch_bounds__(256) void prep_kernel(
    const float* __restrict__ x, const float* __restrict__ weight,
    const float* __restrict__ diag, const float* __restrict__ phi,
    float* __restrict__ scores_t, bf16* __restrict__ wt, bf16* __restrict__ xh)
{
  int blk = blockIdx.x, tid = threadIdx.x;
  if (blk < BT / 4) {
    // ---- scores + head-major bf16 copy: one wave per token ----
    int wave = tid >> 6, lane = tid & 63;
    int token = blk * 4 + wave;
    const floatx4* xr = (const floatx4*)(x + (size_t)token * DIN);
    const floatx4* dg = (const floatx4*)diag;
    floatx4 acc[NK];
#pragma unroll
    for (int k = 0; k < NK; k++) acc[k] = (floatx4){0.f, 0.f, 0.f, 0.f};
#pragma unroll
    for (int it = 0; it < 4; it++) {
      floatx4 xv = xr[it * 64 + lane];
      int col = it * 256 + lane * 4;
      int h = col >> 6, c = col & 63;
      bf16x4 cv;
      cv[0] = (bf16)xv[0]; cv[1] = (bf16)xv[1];
      cv[2] = (bf16)xv[2]; cv[3] = (bf16)xv[3];
      *(bf16x4*)(xh + ((size_t)h * BT + token) * 64 + c) = cv;
#pragma unroll
      for (int k = 0; k < NK; k++) {
        floatx4 dv = dg[k * 256 + it * 64 + lane];
        acc[k] += xv * dv;
      }
    }
    float r[NK];
#pragma unroll
    for (int k = 0; k < NK; k++)
      r[k] = (acc[k][0] + acc[k][1]) + (acc[k][2] + acc[k][3]);
#pragma unroll
    for (int k = 0; k < NK; k++) {
      float v = r[k];
#pragma unroll
      for (int off = 32; off >= 1; off >>= 1) v += __shfl_xor(v, off, 64);
      r[k] = v;
    }
    if (lane == 0) {
      int t = token & (SEQ_T - 1);
#pragma unroll
      for (int k = 0; k < NK; k++)
        scores_t[(size_t)k * BT + token] = phi[t * NK + k] + r[k];
    }
  } else {
    // ---- weight transpose: one (h,k) 64x64 tile per block, coalesced ----
    __shared__ bf16 tile[64 * 68];
    int hk = blk - BT / 4;
    const float* wsrc = weight + (size_t)hk * DH * DO;
#pragma unroll
    for (int it = 0; it < 4; it++) {
      int idx = it * 1024 + tid * 4;
      int i = idx >> 6, o = idx & 63;
      floatx4 v = *(const floatx4*)(wsrc + idx);
#pragma unroll
      for (int r = 0; r < 4; r++)
        tile[(o + r) * 68 + i] = (bf16)v[r];
    }
    __syncthreads();
#pragma unroll
    for (int it = 0; it < 4; it++) {
      int idx = it * 1024 + tid * 4;
      int o2 = idx >> 6, i2 = idx & 63;
      bf16x4 v = *(const bf16x4*)&tile[o2 * 68 + i2];
      *(bf16x4*)(wt + (size_t)hk * 4096 + idx) = v;
    }
  }
}

// ---------------------------------------------------------------------------
// Kernel 2 (v6): ALL-LDS operands, XOR-swizzled (no padding).
// Block = (128-token group g, head h, col-half nh), 256 threads / 4 waves.
// LDS: x 16 KB + W-half 32 KB + scores 4 KB = 52 KB -> 3 blocks/CU
// (__launch_bounds__(256,3); 159744 B <= 160 KiB). Rows are 64 bf16 = 128 B
// = one full bank wrap, so chunk swizzle phys = c ^ (row&7) makes every
// ds_read/write_b128 exactly 2-way bank-aliased (free, m136).
// ---------------------------------------------------------------------------
__global__ __launch_bounds__(256, 3) void moe_kernel(
    const bf16* __restrict__ xh, const bf16* __restrict__ wt,
    const float* __restrict__ scores_t, float* __restrict__ out)
{
  __shared__ bf16  xl[128 * 64];        // 16384 B
  __shared__ bf16  wl[256 * 64];        // 32768 B  (rows R = e*32 + o)
  __shared__ float sl[NK * 128];        //  4096 B

  int bid = blockIdx.x;
  int g  = bid >> 5;            // 0..63  (128-token groups)
  int h  = (bid >> 1) & 15;
  int nh = bid & 1;             // col half (32 of the head's 64 out-cols)
  int tid = threadIdx.x, lane = tid & 63, w = tid >> 6;
  int l15 = lane & 15, q = lane >> 4;

  // ---- stage x tile: 1024 16-B chunks, swizzled ----
  {
    const bf16* xs = xh + ((size_t)h * BT + g * 128) * 64;
#pragma unroll
    for (int it = 0; it < 4; it++) {
      int idx = it * 256 + tid;
      int row = idx >> 3, c = idx & 7, pc = c ^ (row & 7);
      bf16x8 v = *(const bf16x8*)(xs + idx * 8);
      *(bf16x8*)(xl + row * 64 + pc * 8) = v;
    }
  }
  // ---- stage W half: 8 experts x 32 o-rows x 64 (2048 chunks), swizzled ----
  {
#pragma unroll
    for (int it = 0; it < 8; it++) {
      int idx = it * 256 + tid;               // 0..2047
      int R = idx >> 3, c = idx & 7;          // R = e*32 + o
      int e = R >> 5, o = R & 31;
      bf16x8 v = *(const bf16x8*)(wt + ((size_t)(h * NK + e) * DO + nh * 32 + o) * 64 + c * 8);
      int pc = c ^ (R & 7);
      *(bf16x8*)(wl + R * 64 + pc * 8) = v;
    }
  }
  // ---- stage scores: 8 experts x 128 tokens fp32 ----
  {
    int k = tid >> 5, t4 = (tid & 31) * 4;
    floatx4 v = *(const floatx4*)(scores_t + (size_t)k * BT + g * 128 + t4);
    *(floatx4*)(sl + k * 128 + t4) = v;
  }
  __syncthreads();

  int mh = w >> 1;              // token half (64 rows)
  int ns = w & 1;               // 16-col slice within the 32-col half

  // ---- B fragments: B[i=ki*32+q*8+j][o=ns*16+l15], all 8 experts ----
  bf16x8 b[NK][2];
#pragma unroll
  for (int e = 0; e < NK; e++) {
    int R = e * 32 + ns * 16 + l15;
#pragma unroll
    for (int ki = 0; ki < 2; ki++) {
      int pc = (ki * 4 + q) ^ (R & 7);
      b[e][ki] = *(const bf16x8*)(wl + R * 64 + pc * 8);
    }
  }

#pragma unroll
  for (int m = 0; m < 4; m++) {
    int tr = mh * 64 + m * 16;                 // token row base in block
    int row = tr + l15;
    int p0 = q ^ (row & 7), p1 = (q + 4) ^ (row & 7);
    bf16x8 a0 = *(const bf16x8*)(xl + row * 64 + p0 * 8);
    bf16x8 a1 = *(const bf16x8*)(xl + row * 64 + p1 * 8);
    floatx4 y = (floatx4){0.f, 0.f, 0.f, 0.f};
#pragma unroll
    for (int e = 0; e < NK; e++) {
      floatx4 s4 = *(const floatx4*)(sl + e * 128 + tr + q * 4);
      floatx4 z = (floatx4){0.f, 0.f, 0.f, 0.f};
      z = __builtin_amdgcn_mfma_f32_16x16x32_bf16(a0, b[e][0], z, 0, 0, 0);
      z = __builtin_amdgcn_mfma_f32_16x16x32_bf16(a1, b[e][1], z, 0, 0, 0);
      y += s4 * z;
    }
    // store: C/D layout col=l15, row=q*4+r
    int orow = g * 128 + tr + q * 4;
    float* op = out + (size_t)orow * (NH * DO) + h * DO + nh * 32 + ns * 16 + l15;
#pragma unroll
    for (int r = 0; r < 4; r++)
      op[(size_t)r * (NH * DO)] = y[r];
  }
}

extern "C" void kernel_launch(void* const* d_in, const int* in_sizes, int n_in,
                              void* d_out, int out_size, void* d_ws, size_t ws_size,
                              hipStream_t stream) {
  const float* x      = (const float*)d_in[0];
  const float* weight = (const float*)d_in[1];
  const float* diag   = (const float*)d_in[2];
  const float* phi    = (const float*)d_in[3];
  float* out = (float*)d_out;

  // workspace: [0,1MiB) wt dense | [2MiB) scores_t 256KiB | [4MiB) xh 16MiB
  bf16*  wt       = (bf16*)d_ws;
  float* scores_t = (float*)((char*)d_ws + (2u << 20));
  bf16*  xh       = (bf16*)((char*)d_ws + (4u << 20));

  prep_kernel<<<BT / 4 + NH * NK, 256, 0, stream>>>(x, weight, diag, phi,
                                                    scores_t, wt, xh);
  // 64 token-groups x 16 heads x 2 col-halves
  moe_kernel<<<64 * NH * 2, 256, 0, stream>>>(xh, wt, scores_t, out);
}